// Round 1
// baseline (298.076 us; speedup 1.0000x reference)
//
#include <hip/hip_runtime.h>
#include <hip/hip_bf16.h>
#include <cstdint>

// MFVI second-order CRF, B=32 S=1024 T=256 W=2 ITER=3.
// msg = Shift(P) @ Wc, M=32768 N=256 K=1024 (4 shift regions).
// Round 6: T3-minimum prefetch pipeline in the iter kernel.
//  - Bs double-buffered (2 x 256x32 = 2x16KB), stage(p+1) issued BEFORE
//    ds_read+MFMA of step p, ONE __syncthreads per 32-k step (the compiler's
//    vmcnt(0) drain then lands after compute -> stage latency hidden).
//  - Ps staged once full-width (68x256, 34.8KB) -- h-loop removed.
//  - LDS 69.6KB -> 2 blocks/CU, matching the 512-block grid (2/CU resident).
//
// ws: Pa bf16 [32][1028][256] @0 | Pb @32MB | WcT bf16 [256][1024] @64MB

typedef __attribute__((ext_vector_type(4))) float f32x4;
typedef __attribute__((ext_vector_type(8))) short bf16x8;

__device__ __forceinline__ void load_lds16(const void* g, void* l) {
    __builtin_amdgcn_global_load_lds(
        (const __attribute__((address_space(1))) void*)g,
        (__attribute__((address_space(3))) void*)l, 16, 0, 0);
}

// ---------------- phase-0 helpers ------------------------------------------
__device__ __forceinline__ void wct_one(const float* __restrict__ trans,
                                        __hip_bfloat16* __restrict__ wct, int e) {
    int n = e >> 10, k = e & 1023;
    int r = k >> 8, kk = k & 255;
    float v;
    if (r == 0)      v = trans[kk * 256 + n];
    else if (r == 1) v = trans[65536 + kk * 256 + n];
    else if (r == 2) v = trans[n * 256 + kk];
    else             v = trans[65536 + n * 256 + kk];
    wct[n * 1024 + k] = __float2bfloat16(v);
}

__device__ __forceinline__ void guard_one(__hip_bfloat16* Pa, __hip_bfloat16* Pb, int g) {
    __hip_bfloat16* P = (g & 32768) ? Pb : Pa;
    int rem = g & 32767;
    int b = rem >> 10, wr = (rem >> 8) & 3, col = rem & 255;
    int row = b * 1028 + ((wr < 2) ? wr : 1024 + wr);   // 0,1,1026,1027
    P[row * 256 + col] = __float2bfloat16(0.f);
}

__device__ __forceinline__ void softmax0_row(const float* __restrict__ unary,
                                             const int* __restrict__ lengths,
                                             __hip_bfloat16* __restrict__ Pa,
                                             int row, int lane) {
    int b = row >> 10, s = row & 1023;
    float mval = (s < lengths[b]) ? 1.f : 0.f;
    float4 x = *((const float4*)(unary + (size_t)row * 256 + lane * 4));
    x.x *= mval; x.y *= mval; x.z *= mval; x.w *= mval;
    float mx = fmaxf(fmaxf(x.x, x.y), fmaxf(x.z, x.w));
    #pragma unroll
    for (int o = 32; o; o >>= 1) mx = fmaxf(mx, __shfl_xor(mx, o));
    float ea = __expf(x.x - mx), eb = __expf(x.y - mx);
    float ec = __expf(x.z - mx), ed = __expf(x.w - mx);
    float sum = ea + eb + ec + ed;
    #pragma unroll
    for (int o = 32; o; o >>= 1) sum += __shfl_xor(sum, o);
    float inv = 1.0f / sum;
    union { ushort4 u; __hip_bfloat16 h[4]; } o4;
    o4.h[0] = __float2bfloat16(ea * inv);
    o4.h[1] = __float2bfloat16(eb * inv);
    o4.h[2] = __float2bfloat16(ec * inv);
    o4.h[3] = __float2bfloat16(ed * inv);
    *((ushort4*)(Pa + ((size_t)b * 1028 + 2 + s) * 256 + lane * 4)) = o4.u;
}

__global__ __launch_bounds__(256) void prep_softmax0(
    const float* __restrict__ unary, const float* __restrict__ trans,
    const int* __restrict__ lengths,
    __hip_bfloat16* __restrict__ Pa, __hip_bfloat16* __restrict__ Pb,
    __hip_bfloat16* __restrict__ WcT)
{
    int tid = threadIdx.x, lane = tid & 63, wid = tid >> 6;
    int blk = blockIdx.x;                      // 0..511
    int e0 = (blk * 256 + tid) * 2;
    wct_one(trans, WcT, e0);
    wct_one(trans, WcT, e0 + 1);
    int idx = blk * 256 + tid;
    if (idx < 65536) guard_one(Pa, Pb, idx);
    for (int q = 0; q < 16; ++q)
        softmax0_row(unary, lengths, Pa, blk * 64 + wid * 16 + q, lane);
}

// ---------------- iteration kernel -----------------------------------------
// Block: 512 threads = 8 waves. M-tile 64 x N 256. Wave w: rows (w>>2)*32..+31,
// cols (w&3)*64..+63. Ps (A, 68x256) staged once by DMA; Bs (WcT 32-k slice)
// double-buffered, prefetched one step ahead.
__global__ __launch_bounds__(512, 4) void mfvi_iter_k(
    const __hip_bfloat16* __restrict__ Pin,   // [32][1028][256] padded
    const __hip_bfloat16* __restrict__ WcT,   // [256][1024]
    const float* __restrict__ unary, const int* __restrict__ lengths,
    const float* __restrict__ startT, const float* __restrict__ endT,
    __hip_bfloat16* __restrict__ Pout, float* __restrict__ out, int final_it)
{
    __shared__ __hip_bfloat16 Ps[68 * 256];       // 34816 B
    __shared__ __hip_bfloat16 Bs[2 * 256 * 32];   // 2 x 16384 B
    __shared__ float redA[256];                   // [nslice][row]
    __shared__ float redB[256];

    int tid = threadIdx.x;
    int lane = tid & 63, w = tid >> 6;
    int cn = lane & 15, quad = lane >> 4;
    int wm = (w >> 2) * 32, wn = (w & 3) * 64;
    int nslice = w & 3;
    int tile = blockIdx.x;
    int b = tile >> 4, s0 = (tile & 15) << 6;
    int len = lengths[b];
    const char* Pbase = (const char*)(Pin + ((size_t)b * 1028 + s0) * 256);

    f32x4 acc[2][4] = {};

    // ---- stage Ps once: rows s0-2..s0+65 (padded rows 0..67), 256 cols.
    // 68 rows x 32 chunks = 2176 x 16B. LDS slot c = row*32+ch holds global
    // chunk (ch&~7)|((ch^row)&7)  (XOR swizzle -> 2-way-free ds_read_b128).
    #pragma unroll
    for (int t = 0; t < 5; ++t) {
        int c = t * 512 + tid;
        if (t < 4 || tid < 128) {
            int row = c >> 5, ch = c & 31;
            int gch = (ch & ~7) | ((ch ^ row) & 7);
            load_lds16(Pbase + row * 512 + gch * 16, (char*)Ps + c * 16);
        }
    }

    // Bs stage for K-step p into buffer bb: 256 rows x 32 k = 1024 x 16B,
    // 2 chunks/thread, coalesced DMA. Slot (n, cs) holds global chunk
    // cs ^ ((n>>1)&3)  (row stride 64B -> XOR with (n>>1)&3 spreads 16 lanes
    // over all 32 banks, 2-way-free).
    auto stageB = [&](int bb, int p) {
        int koff = p * 64;                    // byte offset of k0 in a WcT row
        #pragma unroll
        for (int c = 0; c < 2; ++c) {
            int sl = c * 512 + tid;
            int n = sl >> 2, cs = sl & 3;
            int g = cs ^ ((n >> 1) & 3);
            load_lds16((const char*)WcT + n * 2048 + koff + g * 16,
                       (char*)Bs + bb * 16384 + sl * 16);
        }
    };

    stageB(0, 0);
    __syncthreads();          // drains Ps + Bs[0] DMA

    // ---- main loop: 32 steps of K=32, ONE barrier per step, next Bs tile
    // prefetched before compute so its latency hides under ds_read+MFMA.
    #pragma unroll 2
    for (int p = 0; p < 32; ++p) {
        if (p < 31) stageB((p + 1) & 1, p + 1);

        int region = p >> 3;
        int delta = (region == 0) ? -1 : (region == 1) ? -2
                  : (region == 2) ?  1 : 2;
        int gcb = (p & 7) * 4 + quad;         // A chunk within 256-col row

        bf16x8 af[2], bfv[4];
        #pragma unroll
        for (int i = 0; i < 2; ++i) {
            int r = wm + (i << 4) + cn + delta + 2;     // 0..67
            int slot = (gcb & ~7) | ((gcb ^ r) & 7);
            af[i] = *(const bf16x8*)((const char*)Ps + r * 512 + slot * 16);
        }
        #pragma unroll
        for (int j = 0; j < 4; ++j) {
            int n = wn + (j << 4) + cn;
            int cs = quad ^ ((n >> 1) & 3);
            bfv[j] = *(const bf16x8*)((const char*)Bs + (p & 1) * 16384 + n * 64 + cs * 16);
        }
        #pragma unroll
        for (int i = 0; i < 2; ++i)
            #pragma unroll
            for (int j = 0; j < 4; ++j)
                acc[i][j] = __builtin_amdgcn_mfma_f32_16x16x32_bf16(
                    af[i], bfv[j], acc[i][j], 0, 0, 0);

        __syncthreads();      // vmcnt(0) drain lands AFTER compute
    }

    // boundary + unary + mask. C/D: col=lane&15, row=quad*4+reg
    #pragma unroll
    for (int i = 0; i < 2; ++i)
        #pragma unroll
        for (int j = 0; j < 4; ++j) {
            int n = wn + (j << 4) + cn;
            #pragma unroll
            for (int r = 0; r < 4; ++r) {
                int s = s0 + wm + (i << 4) + (quad << 2) + r;
                float x = acc[i][j][r];
                if (s == 0)       x += startT[n];
                if (s == 1)       x += startT[256 + n];
                if (s == len - 1) x += endT[n];
                if (s == len - 2) x += endT[256 + n];
                long idx = ((long)((b << 10) + s)) * 256 + n;
                x += unary[idx];
                acc[i][j][r] = (s < len) ? x : 0.f;
            }
        }

    if (final_it) {
        #pragma unroll
        for (int i = 0; i < 2; ++i)
            #pragma unroll
            for (int j = 0; j < 4; ++j) {
                int n = wn + (j << 4) + cn;
                #pragma unroll
                for (int r = 0; r < 4; ++r) {
                    int s = s0 + wm + (i << 4) + (quad << 2) + r;
                    out[((long)((b << 10) + s)) * 256 + n] = acc[i][j][r];
                }
            }
        return;
    }

    // fused row softmax over 256 cols: quad shfl-reduce, then combine the
    // 4 N-slices via LDS. redA[nslice][row(0..63)]
    #pragma unroll
    for (int i = 0; i < 2; ++i)
        #pragma unroll
        for (int r = 0; r < 4; ++r) {
            float m4 = fmaxf(fmaxf(acc[i][0][r], acc[i][1][r]),
                             fmaxf(acc[i][2][r], acc[i][3][r]));
            m4 = fmaxf(m4, __shfl_xor(m4, 1));
            m4 = fmaxf(m4, __shfl_xor(m4, 2));
            m4 = fmaxf(m4, __shfl_xor(m4, 4));
            m4 = fmaxf(m4, __shfl_xor(m4, 8));
            if (cn == 0)
                redA[(nslice << 6) + wm + (i << 4) + (quad << 2) + r] = m4;
        }
    __syncthreads();
    float M[2][4];
    #pragma unroll
    for (int i = 0; i < 2; ++i)
        #pragma unroll
        for (int r = 0; r < 4; ++r) {
            int row = wm + (i << 4) + (quad << 2) + r;
            M[i][r] = fmaxf(fmaxf(redA[row], redA[64 + row]),
                            fmaxf(redA[128 + row], redA[192 + row]));
        }
    #pragma unroll
    for (int i = 0; i < 2; ++i)
        #pragma unroll
        for (int r = 0; r < 4; ++r) {
            float s4 = 0.f;
            #pragma unroll
            for (int j = 0; j < 4; ++j) {
                float e = __expf(acc[i][j][r] - M[i][r]);
                acc[i][j][r] = e;
                s4 += e;
            }
            s4 += __shfl_xor(s4, 1);
            s4 += __shfl_xor(s4, 2);
            s4 += __shfl_xor(s4, 4);
            s4 += __shfl_xor(s4, 8);
            if (cn == 0)
                redB[(nslice << 6) + wm + (i << 4) + (quad << 2) + r] = s4;
        }
    __syncthreads();
    #pragma unroll
    for (int i = 0; i < 2; ++i)
        #pragma unroll
        for (int r = 0; r < 4; ++r) {
            int row = wm + (i << 4) + (quad << 2) + r;
            float inv = 1.0f / (redB[row] + redB[64 + row] +
                                redB[128 + row] + redB[192 + row]);
            int s = s0 + row;
            #pragma unroll
            for (int j = 0; j < 4; ++j) {
                int n = wn + (j << 4) + cn;
                Pout[((size_t)b * 1028 + 2 + s) * 256 + n] =
                    __float2bfloat16(acc[i][j][r] * inv);
            }
        }
}

extern "C" void kernel_launch(void* const* d_in, const int* in_sizes, int n_in,
                              void* d_out, int out_size, void* d_ws, size_t ws_size,
                              hipStream_t stream) {
    const float* unary  = (const float*)d_in[1];
    const float* trans  = (const float*)d_in[3];
    const float* startT = (const float*)d_in[4];
    const float* endT   = (const float*)d_in[5];
    const int*   lens   = (const int*)d_in[6];

    char* ws = (char*)d_ws;
    __hip_bfloat16* Pa  = (__hip_bfloat16*)ws;                          // 16.8 MB
    __hip_bfloat16* Pb  = (__hip_bfloat16*)(ws + ((size_t)32 << 20));   // 16.8 MB
    __hip_bfloat16* WcT = (__hip_bfloat16*)(ws + ((size_t)64 << 20));   // 512 KB
    float* out = (float*)d_out;

    prep_softmax0<<<dim3(512), dim3(256), 0, stream>>>(unary, trans, lens, Pa, Pb, WcT);
    mfvi_iter_k<<<dim3(512), dim3(512), 0, stream>>>(Pa, WcT, unary, lens, startT, endT, Pb, nullptr, 0);
    mfvi_iter_k<<<dim3(512), dim3(512), 0, stream>>>(Pb, WcT, unary, lens, startT, endT, Pa, nullptr, 0);
    mfvi_iter_k<<<dim3(512), dim3(512), 0, stream>>>(Pa, WcT, unary, lens, startT, endT, nullptr, out, 1);
}

// Round 2
// 289.934 us; speedup vs baseline: 1.0281x; 1.0281x over previous
//
#include <hip/hip_runtime.h>
#include <hip/hip_bf16.h>
#include <cstdint>

// MFVI second-order CRF, B=32 S=1024 T=256 W=2 ITER=3.
// msg = Shift(P) @ Wc, M=32768 N=256 K=1024 (4 shift regions).
// Round 7:
//  - prep softmax kernel REMOVED: iter1 computes softmax(masked unary) for
//    its 68-row tile (incl. +-2 halo) in-prologue, fp32 math -> bf16 Ps.
//    Saves the Pa write+read roundtrip (33.6 MB) and a full dispatch.
//  - WcT stored TILED + PRE-SWIZZLED: WcTt[p][sl] 16KB contiguous per K-step,
//    so Bs staging is a linear coalesced global_load_lds stream (m173 pattern).
//  - K-loop keeps round-6 prefetch (Bs dbuf, stage(p+1) before compute(p),
//    one barrier/step).
//
// ws: Pa bf16 [32][1028][256] @0 | Pb @32MB | WcTt bf16 [32][1024]x16B @64MB

typedef __attribute__((ext_vector_type(4))) float f32x4;
typedef __attribute__((ext_vector_type(8))) short bf16x8;

__device__ __forceinline__ void load_lds16(const void* g, void* l) {
    __builtin_amdgcn_global_load_lds(
        (const __attribute__((address_space(1))) void*)g,
        (__attribute__((address_space(3))) void*)l, 16, 0, 0);
}

// ---------------- prep: tiled WcT build + guard rows ------------------------
// WcTt chunk (p, sl): sl = n*4 + cs holds global k-chunk gk = p*4 + (cs ^
// ((n>>1)&3)) of logical WcT row n  (involution matches the K-loop B-read).
__global__ __launch_bounds__(256) void prep_wct(
    const float* __restrict__ trans,
    __hip_bfloat16* __restrict__ Pa, __hip_bfloat16* __restrict__ Pb,
    __hip_bfloat16* __restrict__ WcTt)
{
    int idx = blockIdx.x * 256 + threadIdx.x;
    if (idx < 32768) {
        int p = idx >> 10, sl = idx & 1023;
        int n = sl >> 2, cs = sl & 3;
        int gk = p * 4 + (cs ^ ((n >> 1) & 3));
        union { bf16x8 v; __hip_bfloat16 h[8]; } o;
        #pragma unroll
        for (int e = 0; e < 8; ++e) {
            int k = gk * 8 + e;
            int r = k >> 8, kk = k & 255;
            float v;
            if (r == 0)      v = trans[kk * 256 + n];
            else if (r == 1) v = trans[65536 + kk * 256 + n];
            else if (r == 2) v = trans[n * 256 + kk];
            else             v = trans[65536 + n * 256 + kk];
            o.h[e] = __float2bfloat16(v);
        }
        ((bf16x8*)WcTt)[idx] = o.v;
    } else if (idx < 40960) {
        // zero guard rows (0,1,1026,1027) of Pa and Pb, 16B chunks
        int g = idx - 32768;
        __hip_bfloat16* P = (g & 4096) ? Pb : Pa;
        int rem = g & 4095;
        int b = rem >> 7, wr = (rem >> 5) & 3, ch = rem & 31;
        int row = b * 1028 + ((wr < 2) ? wr : 1024 + wr);
        bf16x8 z = {};
        *(bf16x8*)(P + row * 256 + ch * 8) = z;
    }
}

// ---------------- iteration kernel -----------------------------------------
// Block: 512 threads = 8 waves. M-tile 64 x N 256. Wave w: rows (w>>2)*32..+31,
// cols (w&3)*64..+63. Ps (A, 68x256) staged once (DMA, or in-prologue softmax
// of unary for iter1); Bs (WcTt 32-k tile) double-buffered, prefetched.
__global__ __launch_bounds__(512, 4) void mfvi_iter_k(
    const __hip_bfloat16* __restrict__ Pin,   // [32][1028][256] padded
    const __hip_bfloat16* __restrict__ WcTt,  // [32][1024] x 16B tiles
    const float* __restrict__ unary, const int* __restrict__ lengths,
    const float* __restrict__ startT, const float* __restrict__ endT,
    __hip_bfloat16* __restrict__ Pout, float* __restrict__ out,
    int first_it, int final_it)
{
    __shared__ __hip_bfloat16 Ps[68 * 256];       // 34816 B
    __shared__ __hip_bfloat16 Bs[2 * 256 * 32];   // 2 x 16384 B
    __shared__ float redA[256];                   // [nslice][row]
    __shared__ float redB[256];

    int tid = threadIdx.x;
    int lane = tid & 63, w = tid >> 6;
    int cn = lane & 15, quad = lane >> 4;
    int wm = (w >> 2) * 32, wn = (w & 3) * 64;
    int nslice = w & 3;
    int tile = blockIdx.x;
    int b = tile >> 4, s0 = (tile & 15) << 6;
    int len = lengths[b];

    f32x4 acc[2][4] = {};

    if (first_it) {
        // ---- prologue softmax: P row r (padded 0..67) = softmax(masked
        // unary row s0+r-2), bf16 into swizzled Ps. One row per wave-instr:
        // lane holds 4 cols.
        for (int q = 0; q < 9; ++q) {
            int r = w + q * 8;
            if (r >= 68) break;
            int s = s0 + r - 2;
            int ch = lane >> 1;
            int slot = (ch & ~7) | ((ch ^ r) & 7);
            char* dst = (char*)Ps + r * 512 + slot * 16 + (lane & 1) * 8;
            if (s >= 0 && s < 1024) {
                float mval = (s < len) ? 1.f : 0.f;
                float4 x = *((const float4*)(unary + ((size_t)((b << 10) + s)) * 256 + lane * 4));
                x.x *= mval; x.y *= mval; x.z *= mval; x.w *= mval;
                float mx = fmaxf(fmaxf(x.x, x.y), fmaxf(x.z, x.w));
                #pragma unroll
                for (int o = 32; o; o >>= 1) mx = fmaxf(mx, __shfl_xor(mx, o));
                float ea = __expf(x.x - mx), eb = __expf(x.y - mx);
                float ec = __expf(x.z - mx), ed = __expf(x.w - mx);
                float sum = ea + eb + ec + ed;
                #pragma unroll
                for (int o = 32; o; o >>= 1) sum += __shfl_xor(sum, o);
                float inv = 1.0f / sum;
                union { ushort4 u; __hip_bfloat16 h[4]; } o4;
                o4.h[0] = __float2bfloat16(ea * inv);
                o4.h[1] = __float2bfloat16(eb * inv);
                o4.h[2] = __float2bfloat16(ec * inv);
                o4.h[3] = __float2bfloat16(ed * inv);
                *((ushort4*)dst) = o4.u;
            } else {
                ushort4 z = {0, 0, 0, 0};
                *((ushort4*)dst) = z;
            }
        }
    } else {
        // ---- stage Ps via DMA: rows s0-2..s0+65 (padded 0..67), 256 cols.
        // LDS slot c=row*32+ch holds global chunk (ch&~7)|((ch^row)&7).
        const char* Pbase = (const char*)(Pin + ((size_t)b * 1028 + s0) * 256);
        #pragma unroll
        for (int t = 0; t < 5; ++t) {
            int c = t * 512 + tid;
            if (t < 4 || tid < 128) {
                int row = c >> 5, ch = c & 31;
                int gch = (ch & ~7) | ((ch ^ row) & 7);
                load_lds16(Pbase + row * 512 + gch * 16, (char*)Ps + c * 16);
            }
        }
    }

    // Bs stage for K-step p into buffer bb: linear coalesced copy of the
    // pre-swizzled 16KB tile (2 chunks/thread).
    auto stageB = [&](int bb, int p) {
        #pragma unroll
        for (int c = 0; c < 2; ++c) {
            int sl = c * 512 + tid;
            load_lds16((const char*)WcTt + p * 16384 + sl * 16,
                       (char*)Bs + bb * 16384 + sl * 16);
        }
    };

    stageB(0, 0);
    __syncthreads();          // drains Ps + Bs[0]

    // ---- main loop: 32 steps of K=32, ONE barrier per step, next Bs tile
    // prefetched before compute.
    #pragma unroll 2
    for (int p = 0; p < 32; ++p) {
        if (p < 31) stageB((p + 1) & 1, p + 1);

        int region = p >> 3;
        int delta = (region == 0) ? -1 : (region == 1) ? -2
                  : (region == 2) ?  1 : 2;
        int gcb = (p & 7) * 4 + quad;         // A chunk within 256-col row

        bf16x8 af[2], bfv[4];
        #pragma unroll
        for (int i = 0; i < 2; ++i) {
            int r = wm + (i << 4) + cn + delta + 2;     // 0..67
            int slot = (gcb & ~7) | ((gcb ^ r) & 7);
            af[i] = *(const bf16x8*)((const char*)Ps + r * 512 + slot * 16);
        }
        #pragma unroll
        for (int j = 0; j < 4; ++j) {
            int n = wn + (j << 4) + cn;
            int cs = quad ^ ((n >> 1) & 3);
            bfv[j] = *(const bf16x8*)((const char*)Bs + (p & 1) * 16384 + n * 64 + cs * 16);
        }
        #pragma unroll
        for (int i = 0; i < 2; ++i)
            #pragma unroll
            for (int j = 0; j < 4; ++j)
                acc[i][j] = __builtin_amdgcn_mfma_f32_16x16x32_bf16(
                    af[i], bfv[j], acc[i][j], 0, 0, 0);

        __syncthreads();
    }

    // boundary + unary + mask. C/D: col=lane&15, row=quad*4+reg
    #pragma unroll
    for (int i = 0; i < 2; ++i)
        #pragma unroll
        for (int j = 0; j < 4; ++j) {
            int n = wn + (j << 4) + cn;
            #pragma unroll
            for (int r = 0; r < 4; ++r) {
                int s = s0 + wm + (i << 4) + (quad << 2) + r;
                float x = acc[i][j][r];
                if (s == 0)       x += startT[n];
                if (s == 1)       x += startT[256 + n];
                if (s == len - 1) x += endT[n];
                if (s == len - 2) x += endT[256 + n];
                long idx = ((long)((b << 10) + s)) * 256 + n;
                x += unary[idx];
                acc[i][j][r] = (s < len) ? x : 0.f;
            }
        }

    if (final_it) {
        #pragma unroll
        for (int i = 0; i < 2; ++i)
            #pragma unroll
            for (int j = 0; j < 4; ++j) {
                int n = wn + (j << 4) + cn;
                #pragma unroll
                for (int r = 0; r < 4; ++r) {
                    int s = s0 + wm + (i << 4) + (quad << 2) + r;
                    out[((long)((b << 10) + s)) * 256 + n] = acc[i][j][r];
                }
            }
        return;
    }

    // fused row softmax over 256 cols: quad shfl-reduce, then combine the
    // 4 N-slices via LDS. redA[nslice][row(0..63)]
    #pragma unroll
    for (int i = 0; i < 2; ++i)
        #pragma unroll
        for (int r = 0; r < 4; ++r) {
            float m4 = fmaxf(fmaxf(acc[i][0][r], acc[i][1][r]),
                             fmaxf(acc[i][2][r], acc[i][3][r]));
            m4 = fmaxf(m4, __shfl_xor(m4, 1));
            m4 = fmaxf(m4, __shfl_xor(m4, 2));
            m4 = fmaxf(m4, __shfl_xor(m4, 4));
            m4 = fmaxf(m4, __shfl_xor(m4, 8));
            if (cn == 0)
                redA[(nslice << 6) + wm + (i << 4) + (quad << 2) + r] = m4;
        }
    __syncthreads();
    float M[2][4];
    #pragma unroll
    for (int i = 0; i < 2; ++i)
        #pragma unroll
        for (int r = 0; r < 4; ++r) {
            int row = wm + (i << 4) + (quad << 2) + r;
            M[i][r] = fmaxf(fmaxf(redA[row], redA[64 + row]),
                            fmaxf(redA[128 + row], redA[192 + row]));
        }
    #pragma unroll
    for (int i = 0; i < 2; ++i)
        #pragma unroll
        for (int r = 0; r < 4; ++r) {
            float s4 = 0.f;
            #pragma unroll
            for (int j = 0; j < 4; ++j) {
                float e = __expf(acc[i][j][r] - M[i][r]);
                acc[i][j][r] = e;
                s4 += e;
            }
            s4 += __shfl_xor(s4, 1);
            s4 += __shfl_xor(s4, 2);
            s4 += __shfl_xor(s4, 4);
            s4 += __shfl_xor(s4, 8);
            if (cn == 0)
                redB[(nslice << 6) + wm + (i << 4) + (quad << 2) + r] = s4;
        }
    __syncthreads();
    #pragma unroll
    for (int i = 0; i < 2; ++i)
        #pragma unroll
        for (int r = 0; r < 4; ++r) {
            int row = wm + (i << 4) + (quad << 2) + r;
            float inv = 1.0f / (redB[row] + redB[64 + row] +
                                redB[128 + row] + redB[192 + row]);
            int s = s0 + row;
            #pragma unroll
            for (int j = 0; j < 4; ++j) {
                int n = wn + (j << 4) + cn;
                Pout[((size_t)b * 1028 + 2 + s) * 256 + n] =
                    __float2bfloat16(acc[i][j][r] * inv);
            }
        }
}

extern "C" void kernel_launch(void* const* d_in, const int* in_sizes, int n_in,
                              void* d_out, int out_size, void* d_ws, size_t ws_size,
                              hipStream_t stream) {
    const float* unary  = (const float*)d_in[1];
    const float* trans  = (const float*)d_in[3];
    const float* startT = (const float*)d_in[4];
    const float* endT   = (const float*)d_in[5];
    const int*   lens   = (const int*)d_in[6];

    char* ws = (char*)d_ws;
    __hip_bfloat16* Pa   = (__hip_bfloat16*)ws;                          // 16.8 MB
    __hip_bfloat16* Pb   = (__hip_bfloat16*)(ws + ((size_t)32 << 20));   // 16.8 MB
    __hip_bfloat16* WcTt = (__hip_bfloat16*)(ws + ((size_t)64 << 20));   // 512 KB
    float* out = (float*)d_out;

    prep_wct<<<dim3(160), dim3(256), 0, stream>>>(trans, Pa, Pb, WcTt);
    mfvi_iter_k<<<dim3(512), dim3(512), 0, stream>>>(Pa, WcTt, unary, lens, startT, endT, Pb, nullptr, 1, 0);
    mfvi_iter_k<<<dim3(512), dim3(512), 0, stream>>>(Pb, WcTt, unary, lens, startT, endT, Pa, nullptr, 0, 0);
    mfvi_iter_k<<<dim3(512), dim3(512), 0, stream>>>(Pa, WcTt, unary, lens, startT, endT, nullptr, out, 0, 1);
}